// Round 5
// baseline (635.982 us; speedup 1.0000x reference)
//
#include <hip/hip_runtime.h>

// Problem constants
#define N_NODES 4096
#define E_TOT   12288
#define F_NODE  64
#define F_EDGE  16
#define HDIM    128
#define NLAYER  4
#define NGRAPH  256

typedef _Float16 half8 __attribute__((ext_vector_type(8)));
typedef float    f32x4 __attribute__((ext_vector_type(4)));
typedef float    f32x4v __attribute__((ext_vector_type(4)));

// ---------------------------------------------------------------------------
// Repack e2_w (+e2_b as a 129th K-chunk) into f16 "fragment-major" layout:
// W2F[((l*129 + k)*32 + chunk)*512 + lane*8 + j]
//   chunk = hc*8 + ot ;  h = hc*32 + (lane>>4)*8 + j ;  o = ot*16 + (lane&15)
// v6: one block per (l,k) page.  Coalesced float4 reads -> LDS transpose
// (32 KB) -> coalesced half8 writes (both global sides fully streamed).
// ---------------------------------------------------------------------------
__global__ __launch_bounds__(256)
void k_prep_w2(const float* __restrict__ e2w, const float* __restrict__ e2b,
               _Float16* __restrict__ W2F)
{
    __shared__ _Float16 pg[16384];
    int b = blockIdx.x;                 // 0 .. 4*129-1
    int l = b / 129, k = b - l * 129;
    const float* src = (k < 128) ? (e2w + ((size_t)(l * 128 + k)) * 16384)
                                 : (e2b + (size_t)l * 16384);
    int t = threadIdx.x;
#pragma unroll
    for (int it = 0; it < 16; ++it) {
        int p = it * 1024 + t * 4;      // linear f32 index (h*128+o)
        float4 v = *(const float4*)(src + p);
#pragma unroll
        for (int j4 = 0; j4 < 4; ++j4) {
            int p_ = p + j4;
            int h  = p_ >> 7, o = p_ & 127;
            int idx = ((h >> 5) * 8 + (o >> 4)) * 512
                    + (((h >> 3) & 3) * 16 + (o & 15)) * 8 + (h & 7);
            float val = (j4 == 0) ? v.x : (j4 == 1) ? v.y : (j4 == 2) ? v.z : v.w;
            pg[idx] = (_Float16)val;
        }
    }
    __syncthreads();
    _Float16* dst = W2F + (size_t)b * 16384;
#pragma unroll
    for (int it = 0; it < 8; ++it) {
        int i = it * 2048 + t * 8;
        *(half8*)(dst + i) = *(const half8*)(pg + i);
    }
}

// h = x @ node_w + node_b  (also f16 copy for the gather path)
__global__ __launch_bounds__(128)
void k_node_enc(const float* __restrict__ x, const float* __restrict__ nw,
                const float* __restrict__ nb, float* __restrict__ h,
                _Float16* __restrict__ hf)
{
    __shared__ float xl[F_NODE];
    int n = blockIdx.x, o = threadIdx.x;
    if (o < F_NODE) xl[o] = x[(size_t)n * F_NODE + o];
    __syncthreads();
    float acc = nb[o];
#pragma unroll 8
    for (int f = 0; f < F_NODE; ++f) acc += xl[f] * nw[f * HDIM + o];
    h [(size_t)n * HDIM + o] = acc;
    hf[(size_t)n * HDIM + o] = (_Float16)acc;
}

__global__ void k_deg(const int* __restrict__ dst, int* __restrict__ deg)
{
    int e = blockIdx.x * 256 + threadIdx.x;
    if (e < E_TOT) atomicAdd(&deg[dst[e]], 1);
}

__global__ void k_invd(const int* __restrict__ deg, float* __restrict__ invd)
{
    int n = blockIdx.x * 256 + threadIdx.x;
    if (n < N_NODES) invd[n] = deg[n] > 0 ? 1.0f / (float)deg[n] : 0.0f;
}

// ef = relu(edge_attr @ e1_w[l] + e1_b[l]) stored f16 [E][136] (16B rows;
// col128 = 1.0 bias chunk, cols 129..135 unused).
// 16 edges per block, 256 thr; w1 (8KB) staged in LDS once per block.
#define EF_STRIDE 136
__global__ __launch_bounds__(256)
void k_edge_mlp(const float* __restrict__ ea, const float* __restrict__ w1,
                const float* __restrict__ b1, _Float16* __restrict__ efg)
{
    __shared__ float al[16][17];
    __shared__ float wl[16][HDIM];
    __shared__ float bl[HDIM];
    int t = threadIdx.x, e0 = blockIdx.x * 16;
    if (t < HDIM) bl[t] = b1[t];
    for (int i = t; i < F_EDGE * HDIM; i += 256) wl[i >> 7][i & 127] = w1[i];
    { int i = t; al[i >> 4][i & 15] = ea[(size_t)e0 * F_EDGE + i]; }
    __syncthreads();
    int e = t >> 4, og = t & 15;
    float acc[8];
#pragma unroll
    for (int j = 0; j < 8; ++j) acc[j] = bl[og * 8 + j];
#pragma unroll
    for (int f = 0; f < F_EDGE; ++f) {
        float a = al[e][f];
#pragma unroll
        for (int j = 0; j < 8; ++j) acc[j] += a * wl[f][og * 8 + j];
    }
    half8 o;
#pragma unroll
    for (int j = 0; j < 8; ++j) o[j] = (_Float16)fmaxf(acc[j], 0.f);
    *(half8*)&efg[(size_t)(e0 + e) * EF_STRIDE + og * 8] = o;
    if (og == 0) efg[(size_t)(e0 + e) * EF_STRIDE + 128] = (_Float16)1.0f;
}

// ---------------------------------------------------------------------------
// msg[e,o] = sum_k ef[e,k] * (h[src[e],:] @ W2[k,:,:]) ; atomic scatter-add
// into single agg (k-split partials merge via the atomics).
// v6: barrier-free register streaming with k-split x8 (kcnt 16/17) and
// __launch_bounds__(256,4): >=4 blocks/CU = 16 waves/CU of mutually
// independent work -> TLP hides the per-wave stall gaps that source-level
// prefetch staggering could not (round-4 null result).  One ks per XCD
// (0.53 MB W2 slice L2-resident).  1536 blocks.
// Block 0 additionally zeroes bns1/bns2 for the following k_out.
// ---------------------------------------------------------------------------
#define BM 64
#define KSPLIT 8
__global__ __launch_bounds__(256, 4)
void k_msg(const _Float16* __restrict__ W2L,   // layer base: [129][32][512] f16
           const _Float16* __restrict__ efg,   // [E][136] f16
           const _Float16* __restrict__ hf,    // [N][128] f16
           const int* __restrict__ srcIdx,
           const int* __restrict__ dstIdx,
           float* __restrict__ agg,            // [N][128] f32
           float* __restrict__ bns1,
           float* __restrict__ bns2)
{
    __shared__ _Float16 efs[BM][24];    // local k-slice of ef (<=17 cols + pad)

    const int tid  = threadIdx.x;
    const int lane = tid & 63;
    const int w    = tid >> 6;          // wave 0..3, owns cols [w*32, w*32+32)
    const int lhi  = lane >> 4;         // 0..3
    const int llo  = lane & 15;

    // XCD-grouped decode: bx%8 -> XCD; XCD j serves k-slice j.
    const int bx    = blockIdx.x;
    const int ks    = bx & 7;
    const int tile  = bx >> 3;                            // 0..191
    const int e0    = tile * BM;
    const int kbase = (129 * ks) >> 3;                    // 0,16,32,...,112
    const int kcnt  = ((129 * (ks + 1)) >> 3) - kbase;    // 16 (ks<7) / 17

    // zero BN partial sums for the k_out that follows (stream-ordered)
    if (bx == 0) {
        if (tid < HDIM)            bns1[tid] = 0.f;
        else if (tid < 2 * HDIM)   bns2[tid - HDIM] = 0.f;
    }

    // stage ef k-slice (64 rows x 3 half8)
    if (tid < BM * 3) {
        int r = tid / 3, c = tid - r * 3;
        *(half8*)&efs[r][c * 8] =
            *(const half8*)(efg + (size_t)(e0 + r) * EF_STRIDE + kbase + c * 8);
    }

    // h_src fragments (all 64 rows; every wave needs all rows) in registers
    half8 hs[4][4];
#pragma unroll
    for (int rf = 0; rf < 4; ++rf) {
        int s = srcIdx[e0 + rf * 16 + llo];
        const _Float16* hp = hf + (size_t)s * HDIM + lhi * 8;
#pragma unroll
        for (int hc = 0; hc < 4; ++hc)
            hs[rf][hc] = *(const half8*)(hp + hc * 32);
    }

    // drain all register-bound memory + efs ds_writes BEFORE the loop
    asm volatile("s_waitcnt vmcnt(0) lgkmcnt(0)" ::: "memory");

    __syncthreads();   // efs ready (only barrier in the kernel)

    // B fragment (hc, cf) at bp + kk*16384 + hc*4096 + cf*512 (f16 units)
    const _Float16* bp = W2L + (size_t)kbase * 16384 + (w * 2) * 512 + lane * 8;

#define LDQ(d0, d1, kk, hc) do {                                            \
        const _Float16* p_ = bp + (size_t)(kk) * 16384 + (hc) * 4096;       \
        d0 = *(const half8*)(p_); d1 = *(const half8*)(p_ + 512);           \
    } while (0)

    half8 b00, b01, b10, b11, b20, b21, b30, b31;
    LDQ(b00, b01, 0, 0);
    LDQ(b10, b11, 0, 1);
    LDQ(b20, b21, 0, 2);
    LDQ(b30, b31, 0, 3);

    f32x4 acc[4][2];
#pragma unroll
    for (int rf = 0; rf < 4; ++rf)
#pragma unroll
        for (int cf = 0; cf < 2; ++cf)
#pragma unroll
            for (int d = 0; d < 4; ++d) acc[rf][cf][d] = 0.f;

    for (int kk = 0; kk < kcnt; ++kk) {
        const bool nx = (kk + 1 < kcnt);
        _Float16 efv[4];
#pragma unroll
        for (int rf = 0; rf < 4; ++rf) efv[rf] = efs[rf * 16 + llo][kk];

        // quarter hc=0
#pragma unroll
        for (int rf = 0; rf < 4; ++rf) {
            half8 av = hs[rf][0] * efv[rf];
            acc[rf][0] = __builtin_amdgcn_mfma_f32_16x16x32_f16(av, b00, acc[rf][0], 0, 0, 0);
            acc[rf][1] = __builtin_amdgcn_mfma_f32_16x16x32_f16(av, b01, acc[rf][1], 0, 0, 0);
        }
        if (nx) LDQ(b00, b01, kk + 1, 0);

        // quarter hc=1
#pragma unroll
        for (int rf = 0; rf < 4; ++rf) {
            half8 av = hs[rf][1] * efv[rf];
            acc[rf][0] = __builtin_amdgcn_mfma_f32_16x16x32_f16(av, b10, acc[rf][0], 0, 0, 0);
            acc[rf][1] = __builtin_amdgcn_mfma_f32_16x16x32_f16(av, b11, acc[rf][1], 0, 0, 0);
        }
        if (nx) LDQ(b10, b11, kk + 1, 1);

        // quarter hc=2
#pragma unroll
        for (int rf = 0; rf < 4; ++rf) {
            half8 av = hs[rf][2] * efv[rf];
            acc[rf][0] = __builtin_amdgcn_mfma_f32_16x16x32_f16(av, b20, acc[rf][0], 0, 0, 0);
            acc[rf][1] = __builtin_amdgcn_mfma_f32_16x16x32_f16(av, b21, acc[rf][1], 0, 0, 0);
        }
        if (nx) LDQ(b20, b21, kk + 1, 2);

        // quarter hc=3
#pragma unroll
        for (int rf = 0; rf < 4; ++rf) {
            half8 av = hs[rf][3] * efv[rf];
            acc[rf][0] = __builtin_amdgcn_mfma_f32_16x16x32_f16(av, b30, acc[rf][0], 0, 0, 0);
            acc[rf][1] = __builtin_amdgcn_mfma_f32_16x16x32_f16(av, b31, acc[rf][1], 0, 0, 0);
        }
        if (nx) LDQ(b30, b31, kk + 1, 3);
    }
#undef LDQ

    // epilogue: scatter-add partial msg into agg[dst]
    // C/D layout: col=lane&15, row=(lane>>4)*4+reg
#pragma unroll
    for (int rf = 0; rf < 4; ++rf) {
#pragma unroll
        for (int r = 0; r < 4; ++r) {
            int row = rf * 16 + lhi * 4 + r;
            int d   = dstIdx[e0 + row];
#pragma unroll
            for (int cf = 0; cf < 2; ++cf) {
                int o = w * 32 + cf * 16 + llo;
                atomicAdd(&agg[(size_t)d * HDIM + o], acc[rf][cf][r]);
            }
        }
    }
}

// out = agg*inv_deg + h @ root_w[l] + conv_b[l]   (16 rows per block)
// also accumulates per-channel batch sum / sumsq for BN (fused bn_stats).
__global__ __launch_bounds__(128)
void k_out(const float* __restrict__ agg, const float* __restrict__ invd,
           const float* __restrict__ h, const float* __restrict__ rw,
           const float* __restrict__ cb, float* __restrict__ outb,
           float* __restrict__ bns1, float* __restrict__ bns2)
{
    __shared__ float hl[16][HDIM];
    int n0 = blockIdx.x * 16, o = threadIdx.x;
    for (int r = 0; r < 16; ++r) hl[r][o] = h[(size_t)(n0 + r) * HDIM + o];
    __syncthreads();
    float acc[16];
    float cbv = cb[o];
#pragma unroll
    for (int r = 0; r < 16; ++r)
        acc[r] = agg[(size_t)(n0 + r) * HDIM + o] * invd[n0 + r] + cbv;
    for (int hh = 0; hh < HDIM; ++hh) {
        float wv = rw[hh * HDIM + o];
#pragma unroll
        for (int r = 0; r < 16; ++r) acc[r] += hl[r][hh] * wv;
    }
    float s1 = 0.f, s2 = 0.f;
#pragma unroll
    for (int r = 0; r < 16; ++r) {
        outb[(size_t)(n0 + r) * HDIM + o] = acc[r];
        s1 += acc[r];
        s2 += acc[r] * acc[r];
    }
    atomicAdd(&bns1[o], s1);
    atomicAdd(&bns2[o], s2);
}

// h += relu(bn(out)) with mu/rsig derived inline; refresh hf.
// Non-last layers: zero agg for the next layer's atomics.
// Last layer: fused global-mean-pool scatter (replaces k_pool).
__global__ void k_bn_apply(const float* __restrict__ outb, const float* __restrict__ bns1,
                           const float* __restrict__ bns2, const float* __restrict__ g,
                           const float* __restrict__ b, float* __restrict__ h,
                           _Float16* __restrict__ hf, float* __restrict__ agg,
                           const int* __restrict__ batch, float* __restrict__ pooled,
                           int* __restrict__ cnt, int last)
{
    int i = blockIdx.x * 256 + threadIdx.x;   // < N*128
    int o = i & (HDIM - 1);
    const float inv_n = 1.0f / (float)N_NODES;
    float m   = bns1[o] * inv_n;
    float var = bns2[o] * inv_n - m * m;
    float rs  = rsqrtf(var + 1e-5f);
    float v  = (outb[i] - m) * rs * g[o] + b[o];
    float hn = h[i] + fmaxf(v, 0.f);
    h[i]  = hn;
    hf[i] = (_Float16)hn;
    if (!last) {
        agg[i] = 0.f;
    } else {
        int n  = i >> 7;
        int gg = batch[n];
        atomicAdd(&pooled[(size_t)gg * HDIM + o], hn);
        if (o == 0) atomicAdd(&cnt[gg], 1);
    }
}

__global__ __launch_bounds__(128)
void k_head(const float* __restrict__ pooled, const int* __restrict__ cnt,
            const float* __restrict__ w1, const float* __restrict__ b1,
            const float* __restrict__ w2, const float* __restrict__ b2,
            float* __restrict__ y)
{
    __shared__ float pl[HDIM];
    __shared__ float red[HDIM];
    int g = blockIdx.x, o = threadIdx.x;
    float ic = 1.0f / (float)max(cnt[g], 1);
    pl[o] = pooled[(size_t)g * HDIM + o] * ic;
    __syncthreads();
    float t = b1[o];
#pragma unroll 8
    for (int hh = 0; hh < HDIM; ++hh) t += pl[hh] * w1[hh * HDIM + o];
    t = fmaxf(t, 0.f);
    red[o] = t * w2[o];
    __syncthreads();
    for (int s = 64; s > 0; s >>= 1) {
        if (o < s) red[o] += red[o + s];
        __syncthreads();
    }
    if (o == 0) y[g] = red[0] + b2[0];
}

// ---------------------------------------------------------------------------
extern "C" void kernel_launch(void* const* d_in, const int* in_sizes, int n_in,
                              void* d_out, int out_size, void* d_ws, size_t ws_size,
                              hipStream_t stream)
{
    const float* x      = (const float*)d_in[0];
    const int*   ei     = (const int*)  d_in[1];
    const float* ea     = (const float*)d_in[2];
    const int*   batch  = (const int*)  d_in[3];
    const float* node_w = (const float*)d_in[4];
    const float* node_b = (const float*)d_in[5];
    const float* e1w    = (const float*)d_in[6];
    const float* e1b    = (const float*)d_in[7];
    const float* e2w    = (const float*)d_in[8];
    const float* e2b    = (const float*)d_in[9];
    const float* rw     = (const float*)d_in[10];
    const float* cb     = (const float*)d_in[11];
    const float* bng    = (const float*)d_in[12];
    const float* bnb    = (const float*)d_in[13];
    const float* hw1    = (const float*)d_in[14];
    const float* hb1    = (const float*)d_in[15];
    const float* hw2    = (const float*)d_in[16];
    const float* hb2    = (const float*)d_in[17];
    float* y = (float*)d_out;

    // workspace carve-up (~27.8 MB, all 256B-aligned chunks)
    char* ws = (char*)d_ws;
    _Float16* W2F  = (_Float16*)ws; ws += 16908288;  // 4*129*16384 f16
    float*    h    = (float*)ws;    ws += 2097152;
    _Float16* hf   = (_Float16*)ws; ws += 1048576;
    _Float16* efg  = (_Float16*)ws; ws += 3342336;   // E*136 f16
    float*    agg  = (float*)ws;    ws += 2097152;   // [N][128] f32
    float*    bns1 = (float*)ws;    ws += 512;       // BN sum
    float*    bns2 = (float*)ws;    ws += 512;       // BN sumsq
    float*    outb = (float*)ws;    ws += 2097152;
    int*      deg  = (int*)ws;      ws += 16384;
    float*    invd = (float*)ws;    ws += 16384;
    float*    pooled = (float*)ws;  ws += 131072;
    int*      cnt  = (int*)ws;      ws += 1024;

    const int* src = ei;
    const int* dst = ei + E_TOT;

    k_prep_w2<<<NLAYER * 129, 256, 0, stream>>>(e2w, e2b, W2F);
    k_node_enc<<<N_NODES, 128, 0, stream>>>(x, node_w, node_b, h, hf);
    hipMemsetAsync(deg, 0, N_NODES * sizeof(int), stream);
    k_deg<<<(E_TOT + 255) / 256, 256, 0, stream>>>(dst, deg);
    k_invd<<<(N_NODES + 255) / 256, 256, 0, stream>>>(deg, invd);
    // agg zero for layer 0; pooled+cnt zero (contiguous => one memset)
    hipMemsetAsync(agg, 0, (size_t)N_NODES * HDIM * sizeof(float), stream);
    hipMemsetAsync(pooled, 0, (size_t)NGRAPH * HDIM * sizeof(float) + NGRAPH * sizeof(int), stream);

    for (int l = 0; l < NLAYER; ++l) {
        k_edge_mlp<<<E_TOT / 16, 256, 0, stream>>>(ea, e1w + l * F_EDGE * HDIM,
                                                   e1b + l * HDIM, efg);
        k_msg<<<(E_TOT / BM) * KSPLIT, 256, 0, stream>>>(
            W2F + (size_t)l * 129 * 16384, efg, hf, src, dst, agg, bns1, bns2);
        k_out<<<N_NODES / 16, 128, 0, stream>>>(agg, invd, h,
                                                rw + l * HDIM * HDIM,
                                                cb + l * HDIM, outb, bns1, bns2);
        k_bn_apply<<<(N_NODES * HDIM) / 256, 256, 0, stream>>>(
            outb, bns1, bns2, bng + l * HDIM, bnb + l * HDIM, h, hf,
            agg, batch, pooled, cnt, (l == NLAYER - 1) ? 1 : 0);
    }

    k_head<<<NGRAPH, 128, 0, stream>>>(pooled, cnt, hw1, hb1, hw2, hb2, y);
}

// Round 6
// 444.503 us; speedup vs baseline: 1.4308x; 1.4308x over previous
//
#include <hip/hip_runtime.h>

// Problem constants
#define N_NODES 4096
#define E_TOT   12288
#define F_NODE  64
#define F_EDGE  16
#define HDIM    128
#define NLAYER  4
#define NGRAPH  256

typedef _Float16 half8 __attribute__((ext_vector_type(8)));
typedef float    f32x4 __attribute__((ext_vector_type(4)));

// ---------------------------------------------------------------------------
// Repack e2_w (+e2_b as a 129th K-chunk) into f16 "fragment-major" layout:
// W2F[((l*129 + k)*32 + chunk)*512 + lane*8 + j]
//   chunk = hc*8 + ot ;  h = hc*32 + (lane>>4)*8 + j ;  o = ot*16 + (lane&15)
// One block per (l,k) page: coalesced float4 reads -> LDS transpose ->
// coalesced half8 writes.
// ---------------------------------------------------------------------------
__global__ __launch_bounds__(256)
void k_prep_w2(const float* __restrict__ e2w, const float* __restrict__ e2b,
               _Float16* __restrict__ W2F)
{
    __shared__ _Float16 pg[16384];
    int b = blockIdx.x;                 // 0 .. 4*129-1
    int l = b / 129, k = b - l * 129;
    const float* src = (k < 128) ? (e2w + ((size_t)(l * 128 + k)) * 16384)
                                 : (e2b + (size_t)l * 16384);
    int t = threadIdx.x;
#pragma unroll
    for (int it = 0; it < 16; ++it) {
        int p = it * 1024 + t * 4;      // linear f32 index (h*128+o)
        float4 v = *(const float4*)(src + p);
#pragma unroll
        for (int j4 = 0; j4 < 4; ++j4) {
            int p_ = p + j4;
            int h  = p_ >> 7, o = p_ & 127;
            int idx = ((h >> 5) * 8 + (o >> 4)) * 512
                    + (((h >> 3) & 3) * 16 + (o & 15)) * 8 + (h & 7);
            float val = (j4 == 0) ? v.x : (j4 == 1) ? v.y : (j4 == 2) ? v.z : v.w;
            pg[idx] = (_Float16)val;
        }
    }
    __syncthreads();
    _Float16* dst = W2F + (size_t)b * 16384;
#pragma unroll
    for (int it = 0; it < 8; ++it) {
        int i = it * 2048 + t * 8;
        *(half8*)(dst + i) = *(const half8*)(pg + i);
    }
}

// h = x @ node_w + node_b  (also f16 copy for the gather path)
__global__ __launch_bounds__(128)
void k_node_enc(const float* __restrict__ x, const float* __restrict__ nw,
                const float* __restrict__ nb, float* __restrict__ h,
                _Float16* __restrict__ hf)
{
    __shared__ float xl[F_NODE];
    int n = blockIdx.x, o = threadIdx.x;
    if (o < F_NODE) xl[o] = x[(size_t)n * F_NODE + o];
    __syncthreads();
    float acc = nb[o];
#pragma unroll 8
    for (int f = 0; f < F_NODE; ++f) acc += xl[f] * nw[f * HDIM + o];
    h [(size_t)n * HDIM + o] = acc;
    hf[(size_t)n * HDIM + o] = (_Float16)acc;
}

__global__ void k_deg(const int* __restrict__ dst, int* __restrict__ deg)
{
    int e = blockIdx.x * 256 + threadIdx.x;
    if (e < E_TOT) atomicAdd(&deg[dst[e]], 1);
}

__global__ void k_invd(const int* __restrict__ deg, float* __restrict__ invd)
{
    int n = blockIdx.x * 256 + threadIdx.x;
    if (n < N_NODES) invd[n] = deg[n] > 0 ? 1.0f / (float)deg[n] : 0.0f;
}

// ef = relu(edge_attr @ e1_w[l] + e1_b[l]) stored f16 [E][136] (16B rows;
// col128 = 1.0 bias chunk, cols 129..135 unused).
// 16 edges per block, 256 thr; w1 (8KB) staged in LDS once per block.
#define EF_STRIDE 136
__global__ __launch_bounds__(256)
void k_edge_mlp(const float* __restrict__ ea, const float* __restrict__ w1,
                const float* __restrict__ b1, _Float16* __restrict__ efg)
{
    __shared__ float al[16][17];
    __shared__ float wl[16][HDIM];
    __shared__ float bl[HDIM];
    int t = threadIdx.x, e0 = blockIdx.x * 16;
    if (t < HDIM) bl[t] = b1[t];
    for (int i = t; i < F_EDGE * HDIM; i += 256) wl[i >> 7][i & 127] = w1[i];
    { int i = t; al[i >> 4][i & 15] = ea[(size_t)e0 * F_EDGE + i]; }
    __syncthreads();
    int e = t >> 4, og = t & 15;
    float acc[8];
#pragma unroll
    for (int j = 0; j < 8; ++j) acc[j] = bl[og * 8 + j];
#pragma unroll
    for (int f = 0; f < F_EDGE; ++f) {
        float a = al[e][f];
#pragma unroll
        for (int j = 0; j < 8; ++j) acc[j] += a * wl[f][og * 8 + j];
    }
    half8 o;
#pragma unroll
    for (int j = 0; j < 8; ++j) o[j] = (_Float16)fmaxf(acc[j], 0.f);
    *(half8*)&efg[(size_t)(e0 + e) * EF_STRIDE + og * 8] = o;
    if (og == 0) efg[(size_t)(e0 + e) * EF_STRIDE + 128] = (_Float16)1.0f;
}

// ---------------------------------------------------------------------------
// msg[e,o] = sum_k ef[e,k] * (h[src[e],:] @ W2[k,:,:]) ; atomic scatter-add
// into agg (k-split partials merge via the atomics).
// v7: per-CU L2 load-port was the wall (96KB/iter/CU ~= 61 B/cyc vs ~56
// achievable).  Fix: stage each 32KB B-chunk ONCE per CU into LDS
// (global_load_lds, waves 0-7) and serve the 3 row-groups from the LDS pipe.
// BM=192 edges/block, 12 waves (3 row-groups x 4 col-groups), KSPLIT=4,
// grid = 64*4 = 256 blocks = exactly 1/CU (fixes round-2's 25% idle CUs).
// Double-buffered chunks with counted vmcnt(4) -- never drained to 0 in the
// main loop; 2 barriers/iter.  ks on XCD pairs (atomic profile of round 4).
// ---------------------------------------------------------------------------
#define BM 192
#define KSPLIT 4
__global__ __launch_bounds__(768, 3)
void k_msg(const _Float16* __restrict__ W2L,   // layer base: [129][32][512] f16
           const _Float16* __restrict__ efg,   // [E][136] f16
           const _Float16* __restrict__ hf,    // [N][128] f16
           const int* __restrict__ srcIdx,
           const int* __restrict__ dstIdx,
           float* __restrict__ agg,            // [N][128] f32
           float* __restrict__ bns1,
           float* __restrict__ bns2)
{
    __shared__ _Float16 Bb[2][16384];   // 2 x 32 KB B-chunk double buffer
    __shared__ _Float16 efs[BM][40];    // local k-slice of ef (<=33 cols + pad)

    const int tid  = threadIdx.x;
    const int lane = tid & 63;
    const int w    = tid >> 6;          // wave 0..11
    const int rq   = w >> 2;            // row-group: 64 edges
    const int ch   = w & 3;             // col-group: 32 outputs
    const int lhi  = lane >> 4;         // 0..3
    const int llo  = lane & 15;

    // XCD-grouped decode (bx%8 -> XCD): XCD pair {2ks,2ks+1} serves slice ks.
    const int bx    = blockIdx.x;
    const int ks    = (bx & 7) >> 1;
    const int tile  = (bx >> 3) * 2 + (bx & 1);           // 0..63
    const int e0    = tile * BM;
    const int kbase = (129 * ks) >> 2;                    // 0,32,64,96
    const int kcnt  = ((129 * (ks + 1)) >> 2) - kbase;    // 32,32,32,33

    // zero BN partial sums for the k_out that follows (stream-ordered)
    if (bx == 0) {
        if (tid < HDIM)            bns1[tid] = 0.f;
        else if (tid < 2 * HDIM)   bns2[tid - HDIM] = 0.f;
    }

    // h_src fragments (this wave's 64 rows) resident in registers, f16
    half8 hs[4][4];
#pragma unroll
    for (int rf = 0; rf < 4; ++rf) {
        int s = srcIdx[e0 + rq * 64 + rf * 16 + llo];
        const _Float16* hp = hf + (size_t)s * HDIM + lhi * 8;
#pragma unroll
        for (int hc = 0; hc < 4; ++hc)
            hs[rf][hc] = *(const half8*)(hp + hc * 32);
    }

    // per-k B chunk = 32 KB; waves 0..7 stage 4 KB each = 4 x 1KB DMA
    auto STAGE = [&](int kg, int buf) {
        const _Float16* g = W2L + (size_t)kg * 16384 + w * 2048 + lane * 8;
        _Float16* lp = &Bb[buf][w * 2048];
#pragma unroll
        for (int i = 0; i < 4; ++i)
            __builtin_amdgcn_global_load_lds(
                (const __attribute__((address_space(1))) void*)(g + i * 512),
                (__attribute__((address_space(3))) void*)(lp + i * 512), 16, 0, 0);
    };

    if (w < 8) STAGE(kbase + 0, 0);

    // stage ef k-slice (192 rows x 5 half8)
    for (int i = tid; i < BM * 5; i += 768) {
        int r = i / 5, c = i - r * 5;
        *(half8*)&efs[r][c * 8] =
            *(const half8*)(efg + (size_t)(e0 + r) * EF_STRIDE + kbase + c * 8);
    }

    __syncthreads();   // efs ready

    f32x4 acc[4][2];
#pragma unroll
    for (int rf = 0; rf < 4; ++rf)
#pragma unroll
        for (int cf = 0; cf < 2; ++cf)
#pragma unroll
            for (int d = 0; d < 4; ++d) acc[rf][cf][d] = 0.f;

    for (int kk = 0; kk < kcnt; ++kk) {
        const int  cur = kk & 1;
        const bool nx  = (kk + 1 < kcnt);
        // barrier1: all waves done reading Bb[cur^1] (iter kk-1)
        asm volatile("" ::: "memory");
        __builtin_amdgcn_s_barrier();
        asm volatile("" ::: "memory");
        if (w < 8) {
            if (nx) {
                STAGE(kbase + kk + 1, cur ^ 1);
                // wait own stage(kk) 4 DMAs; stage(kk+1)'s 4 stay in flight
                asm volatile("s_waitcnt vmcnt(4)" ::: "memory");
            } else {
                asm volatile("s_waitcnt vmcnt(0)" ::: "memory");
            }
        }
        asm volatile("" ::: "memory");
        __builtin_amdgcn_s_barrier();
        asm volatile("" ::: "memory");

        // ef scalars for this k (16 rows per rf, broadcast across lhi groups)
        _Float16 efv[4];
#pragma unroll
        for (int rf = 0; rf < 4; ++rf) efv[rf] = efs[rq * 64 + rf * 16 + llo][kk];

        const _Float16* bb = &Bb[cur][ch * 1024 + lane * 8];
#pragma unroll
        for (int hc = 0; hc < 4; ++hc) {
            half8 bfr[2];
#pragma unroll
            for (int cf = 0; cf < 2; ++cf)       // chunk = hc*8 + ch*2 + cf
                bfr[cf] = *(const half8*)(bb + hc * 4096 + cf * 512);
#pragma unroll
            for (int rf = 0; rf < 4; ++rf) {
                half8 av = hs[rf][hc] * efv[rf];   // v_pk_mul_f16
                acc[rf][0] = __builtin_amdgcn_mfma_f32_16x16x32_f16(
                    av, bfr[0], acc[rf][0], 0, 0, 0);
                acc[rf][1] = __builtin_amdgcn_mfma_f32_16x16x32_f16(
                    av, bfr[1], acc[rf][1], 0, 0, 0);
            }
        }
    }

    // epilogue: scatter-add partial msg into agg[dst]
    // C/D layout: col=lane&15, row=(lane>>4)*4+reg
#pragma unroll
    for (int rf = 0; rf < 4; ++rf) {
#pragma unroll
        for (int r = 0; r < 4; ++r) {
            int row = rq * 64 + rf * 16 + lhi * 4 + r;
            int d   = dstIdx[e0 + row];
#pragma unroll
            for (int cf = 0; cf < 2; ++cf) {
                int o = ch * 32 + cf * 16 + llo;
                atomicAdd(&agg[(size_t)d * HDIM + o], acc[rf][cf][r]);
            }
        }
    }
}

// out = agg*inv_deg + h @ root_w[l] + conv_b[l]   (16 rows per block)
// also accumulates per-channel batch sum / sumsq for BN (fused bn_stats).
__global__ __launch_bounds__(128)
void k_out(const float* __restrict__ agg, const float* __restrict__ invd,
           const float* __restrict__ h, const float* __restrict__ rw,
           const float* __restrict__ cb, float* __restrict__ outb,
           float* __restrict__ bns1, float* __restrict__ bns2)
{
    __shared__ float hl[16][HDIM];
    int n0 = blockIdx.x * 16, o = threadIdx.x;
    for (int r = 0; r < 16; ++r) hl[r][o] = h[(size_t)(n0 + r) * HDIM + o];
    __syncthreads();
    float acc[16];
    float cbv = cb[o];
#pragma unroll
    for (int r = 0; r < 16; ++r)
        acc[r] = agg[(size_t)(n0 + r) * HDIM + o] * invd[n0 + r] + cbv;
    for (int hh = 0; hh < HDIM; ++hh) {
        float wv = rw[hh * HDIM + o];
#pragma unroll
        for (int r = 0; r < 16; ++r) acc[r] += hl[r][hh] * wv;
    }
    float s1 = 0.f, s2 = 0.f;
#pragma unroll
    for (int r = 0; r < 16; ++r) {
        outb[(size_t)(n0 + r) * HDIM + o] = acc[r];
        s1 += acc[r];
        s2 += acc[r] * acc[r];
    }
    atomicAdd(&bns1[o], s1);
    atomicAdd(&bns2[o], s2);
}

// h += relu(bn(out)) with mu/rsig derived inline; refresh hf.
// Non-last layers: zero agg for the next layer's atomics.
// Last layer: fused global-mean-pool scatter (replaces k_pool).
__global__ void k_bn_apply(const float* __restrict__ outb, const float* __restrict__ bns1,
                           const float* __restrict__ bns2, const float* __restrict__ g,
                           const float* __restrict__ b, float* __restrict__ h,
                           _Float16* __restrict__ hf, float* __restrict__ agg,
                           const int* __restrict__ batch, float* __restrict__ pooled,
                           int* __restrict__ cnt, int last)
{
    int i = blockIdx.x * 256 + threadIdx.x;   // < N*128
    int o = i & (HDIM - 1);
    const float inv_n = 1.0f / (float)N_NODES;
    float m   = bns1[o] * inv_n;
    float var = bns2[o] * inv_n - m * m;
    float rs  = rsqrtf(var + 1e-5f);
    float v  = (outb[i] - m) * rs * g[o] + b[o];
    float hn = h[i] + fmaxf(v, 0.f);
    h[i]  = hn;
    hf[i] = (_Float16)hn;
    if (!last) {
        agg[i] = 0.f;
    } else {
        int n  = i >> 7;
        int gg = batch[n];
        atomicAdd(&pooled[(size_t)gg * HDIM + o], hn);
        if (o == 0) atomicAdd(&cnt[gg], 1);
    }
}

__global__ __launch_bounds__(128)
void k_head(const float* __restrict__ pooled, const int* __restrict__ cnt,
            const float* __restrict__ w1, const float* __restrict__ b1,
            const float* __restrict__ w2, const float* __restrict__ b2,
            float* __restrict__ y)
{
    __shared__ float pl[HDIM];
    __shared__ float red[HDIM];
    int g = blockIdx.x, o = threadIdx.x;
    float ic = 1.0f / (float)max(cnt[g], 1);
    pl[o] = pooled[(size_t)g * HDIM + o] * ic;
    __syncthreads();
    float t = b1[o];
#pragma unroll 8
    for (int hh = 0; hh < HDIM; ++hh) t += pl[hh] * w1[hh * HDIM + o];
    t = fmaxf(t, 0.f);
    red[o] = t * w2[o];
    __syncthreads();
    for (int s = 64; s > 0; s >>= 1) {
        if (o < s) red[o] += red[o + s];
        __syncthreads();
    }
    if (o == 0) y[g] = red[0] + b2[0];
}

// ---------------------------------------------------------------------------
extern "C" void kernel_launch(void* const* d_in, const int* in_sizes, int n_in,
                              void* d_out, int out_size, void* d_ws, size_t ws_size,
                              hipStream_t stream)
{
    const float* x      = (const float*)d_in[0];
    const int*   ei     = (const int*)  d_in[1];
    const float* ea     = (const float*)d_in[2];
    const int*   batch  = (const int*)  d_in[3];
    const float* node_w = (const float*)d_in[4];
    const float* node_b = (const float*)d_in[5];
    const float* e1w    = (const float*)d_in[6];
    const float* e1b    = (const float*)d_in[7];
    const float* e2w    = (const float*)d_in[8];
    const float* e2b    = (const float*)d_in[9];
    const float* rw     = (const float*)d_in[10];
    const float* cb     = (const float*)d_in[11];
    const float* bng    = (const float*)d_in[12];
    const float* bnb    = (const float*)d_in[13];
    const float* hw1    = (const float*)d_in[14];
    const float* hb1    = (const float*)d_in[15];
    const float* hw2    = (const float*)d_in[16];
    const float* hb2    = (const float*)d_in[17];
    float* y = (float*)d_out;

    // workspace carve-up (~27.8 MB, all 256B-aligned chunks)
    char* ws = (char*)d_ws;
    _Float16* W2F  = (_Float16*)ws; ws += 16908288;  // 4*129*16384 f16
    float*    h    = (float*)ws;    ws += 2097152;
    _Float16* hf   = (_Float16*)ws; ws += 1048576;
    _Float16* efg  = (_Float16*)ws; ws += 3342336;   // E*136 f16
    float*    agg  = (float*)ws;    ws += 2097152;   // [N][128] f32
    float*    bns1 = (float*)ws;    ws += 512;       // BN sum
    float*    bns2 = (float*)ws;    ws += 512;       // BN sumsq
    float*    outb = (float*)ws;    ws += 2097152;
    int*      deg  = (int*)ws;      ws += 16384;
    float*    invd = (float*)ws;    ws += 16384;
    float*    pooled = (float*)ws;  ws += 131072;
    int*      cnt  = (int*)ws;      ws += 1024;

    const int* src = ei;
    const int* dst = ei + E_TOT;

    k_prep_w2<<<NLAYER * 129, 256, 0, stream>>>(e2w, e2b, W2F);
    k_node_enc<<<N_NODES, 128, 0, stream>>>(x, node_w, node_b, h, hf);
    hipMemsetAsync(deg, 0, N_NODES * sizeof(int), stream);
    k_deg<<<(E_TOT + 255) / 256, 256, 0, stream>>>(dst, deg);
    k_invd<<<(N_NODES + 255) / 256, 256, 0, stream>>>(deg, invd);
    // agg zero for layer 0; pooled+cnt zero (contiguous => one memset)
    hipMemsetAsync(agg, 0, (size_t)N_NODES * HDIM * sizeof(float), stream);
    hipMemsetAsync(pooled, 0, (size_t)NGRAPH * HDIM * sizeof(float) + NGRAPH * sizeof(int), stream);

    for (int l = 0; l < NLAYER; ++l) {
        k_edge_mlp<<<E_TOT / 16, 256, 0, stream>>>(ea, e1w + l * F_EDGE * HDIM,
                                                   e1b + l * HDIM, efg);
        k_msg<<<(E_TOT / BM) * KSPLIT, 768, 0, stream>>>(
            W2F + (size_t)l * 129 * 16384, efg, hf, src, dst, agg, bns1, bns2);
        k_out<<<N_NODES / 16, 128, 0, stream>>>(agg, invd, h,
                                                rw + l * HDIM * HDIM,
                                                cb + l * HDIM, outb, bns1, bns2);
        k_bn_apply<<<(N_NODES * HDIM) / 256, 256, 0, stream>>>(
            outb, bns1, bns2, bng + l * HDIM, bnb + l * HDIM, h, hf,
            agg, batch, pooled, cnt, (l == NLAYER - 1) ? 1 : 0);
    }

    k_head<<<NGRAPH, 128, 0, stream>>>(pooled, cnt, hw1, hb1, hw2, hb2, y);
}

// Round 7
// 421.059 us; speedup vs baseline: 1.5104x; 1.0557x over previous
//
#include <hip/hip_runtime.h>

// Problem constants
#define N_NODES 4096
#define E_TOT   12288
#define F_NODE  64
#define F_EDGE  16
#define HDIM    128
#define NLAYER  4
#define NGRAPH  256

typedef _Float16 half8 __attribute__((ext_vector_type(8)));
typedef float    f32x4 __attribute__((ext_vector_type(4)));

// ---------------------------------------------------------------------------
// Repack e2_w (+e2_b as a 129th K-chunk) into f16 "fragment-major" layout:
// W2F[((l*129 + k)*32 + chunk)*512 + lane*8 + j]
//   chunk = hc*8 + ot ;  h = hc*32 + (lane>>4)*8 + j ;  o = ot*16 + (lane&15)
// One block per (l,k) page: coalesced float4 reads -> LDS transpose ->
// coalesced half8 writes.
// ---------------------------------------------------------------------------
__global__ __launch_bounds__(256)
void k_prep_w2(const float* __restrict__ e2w, const float* __restrict__ e2b,
               _Float16* __restrict__ W2F)
{
    __shared__ _Float16 pg[16384];
    int b = blockIdx.x;                 // 0 .. 4*129-1
    int l = b / 129, k = b - l * 129;
    const float* src = (k < 128) ? (e2w + ((size_t)(l * 128 + k)) * 16384)
                                 : (e2b + (size_t)l * 16384);
    int t = threadIdx.x;
#pragma unroll
    for (int it = 0; it < 16; ++it) {
        int p = it * 1024 + t * 4;      // linear f32 index (h*128+o)
        float4 v = *(const float4*)(src + p);
#pragma unroll
        for (int j4 = 0; j4 < 4; ++j4) {
            int p_ = p + j4;
            int h  = p_ >> 7, o = p_ & 127;
            int idx = ((h >> 5) * 8 + (o >> 4)) * 512
                    + (((h >> 3) & 3) * 16 + (o & 15)) * 8 + (h & 7);
            float val = (j4 == 0) ? v.x : (j4 == 1) ? v.y : (j4 == 2) ? v.z : v.w;
            pg[idx] = (_Float16)val;
        }
    }
    __syncthreads();
    _Float16* dst = W2F + (size_t)b * 16384;
#pragma unroll
    for (int it = 0; it < 8; ++it) {
        int i = it * 2048 + t * 8;
        *(half8*)(dst + i) = *(const half8*)(pg + i);
    }
}

// h = x @ node_w + node_b  (also f16 copy for the gather path)
__global__ __launch_bounds__(128)
void k_node_enc(const float* __restrict__ x, const float* __restrict__ nw,
                const float* __restrict__ nb, float* __restrict__ h,
                _Float16* __restrict__ hf)
{
    __shared__ float xl[F_NODE];
    int n = blockIdx.x, o = threadIdx.x;
    if (o < F_NODE) xl[o] = x[(size_t)n * F_NODE + o];
    __syncthreads();
    float acc = nb[o];
#pragma unroll 8
    for (int f = 0; f < F_NODE; ++f) acc += xl[f] * nw[f * HDIM + o];
    h [(size_t)n * HDIM + o] = acc;
    hf[(size_t)n * HDIM + o] = (_Float16)acc;
}

__global__ void k_deg(const int* __restrict__ dst, int* __restrict__ deg)
{
    int e = blockIdx.x * 256 + threadIdx.x;
    if (e < E_TOT) atomicAdd(&deg[dst[e]], 1);
}

__global__ void k_invd(const int* __restrict__ deg, float* __restrict__ invd)
{
    int n = blockIdx.x * 256 + threadIdx.x;
    if (n < N_NODES) invd[n] = deg[n] > 0 ? 1.0f / (float)deg[n] : 0.0f;
}

// ef = relu(edge_attr @ e1_w[l] + e1_b[l]) stored f16 [E][136] (16B rows;
// col128 = 1.0 bias chunk, cols 129..135 unused).
// 16 edges per block, 256 thr; w1 (8KB) staged in LDS once per block.
#define EF_STRIDE 136
__global__ __launch_bounds__(256)
void k_edge_mlp(const float* __restrict__ ea, const float* __restrict__ w1,
                const float* __restrict__ b1, _Float16* __restrict__ efg)
{
    __shared__ float al[16][17];
    __shared__ float wl[16][HDIM];
    __shared__ float bl[HDIM];
    int t = threadIdx.x, e0 = blockIdx.x * 16;
    if (t < HDIM) bl[t] = b1[t];
    for (int i = t; i < F_EDGE * HDIM; i += 256) wl[i >> 7][i & 127] = w1[i];
    { int i = t; al[i >> 4][i & 15] = ea[(size_t)e0 * F_EDGE + i]; }
    __syncthreads();
    int e = t >> 4, og = t & 15;
    float acc[8];
#pragma unroll
    for (int j = 0; j < 8; ++j) acc[j] = bl[og * 8 + j];
#pragma unroll
    for (int f = 0; f < F_EDGE; ++f) {
        float a = al[e][f];
#pragma unroll
        for (int j = 0; j < 8; ++j) acc[j] += a * wl[f][og * 8 + j];
    }
    half8 o;
#pragma unroll
    for (int j = 0; j < 8; ++j) o[j] = (_Float16)fmaxf(acc[j], 0.f);
    *(half8*)&efg[(size_t)(e0 + e) * EF_STRIDE + og * 8] = o;
    if (og == 0) efg[(size_t)(e0 + e) * EF_STRIDE + 128] = (_Float16)1.0f;
}

// ---------------------------------------------------------------------------
// msg[e,o] = sum_k ef[e,k] * (h[src[e],:] @ W2[k,:,:]) ; atomic scatter-add
// into agg (k-split partials merge via the atomics).
// v8: barrier-free register streaming (round-4 structure, proven 64-66us)
// COL-SPLIT into 2-wave blocks: each block covers 64 output cols, grid =
// 192 tiles x 4 ks x 2 colhalves = 1536 blocks = 6/CU = 3 waves/SIMD of
// mutually independent work (v7's lockstep barriers and v5's atomic blowup
// both avoided: total atomic ops unchanged, one (ks,chH) per XCD).
// Quarter-granular B refill from L2 into VGPRs; setprio(1) around MFMA
// cluster (independent-wave regime where it pays, m191).
// ---------------------------------------------------------------------------
#define BM 64
#define KSPLIT 4
__global__ __launch_bounds__(128, 3)
void k_msg(const _Float16* __restrict__ W2L,   // layer base: [129][32][512] f16
           const _Float16* __restrict__ efg,   // [E][136] f16
           const _Float16* __restrict__ hf,    // [N][128] f16
           const int* __restrict__ srcIdx,
           const int* __restrict__ dstIdx,
           float* __restrict__ agg,            // [N][128] f32
           float* __restrict__ bns1,
           float* __restrict__ bns2)
{
    __shared__ _Float16 efs[BM][40];    // local k-slice of ef (<=33 cols + pad)

    const int tid  = threadIdx.x;
    const int lane = tid & 63;
    const int w    = tid >> 6;          // wave 0..1, owns cols chH*64+w*32 ..+32
    const int lhi  = lane >> 4;         // 0..3
    const int llo  = lane & 15;

    // XCD-grouped decode: bx%8 -> XCD; XCD code = ks*2 + chH (one combo/XCD).
    const int bx    = blockIdx.x;
    const int code  = bx & 7;
    const int ks    = code >> 1;
    const int chH   = code & 1;
    const int tile  = bx >> 3;                            // 0..191
    const int e0    = tile * BM;
    const int kbase = (129 * ks) >> 2;                    // 0,32,64,96
    const int kcnt  = ((129 * (ks + 1)) >> 2) - kbase;    // 32,32,32,33

    // zero BN partial sums for the k_out that follows (stream-ordered)
    if (bx == 0 && tid < HDIM) { bns1[tid] = 0.f; bns2[tid] = 0.f; }

    // stage ef k-slice (64 rows x 5 half8)
    for (int i = tid; i < BM * 5; i += 128) {
        int r = i / 5, c = i - r * 5;
        *(half8*)&efs[r][c * 8] =
            *(const half8*)(efg + (size_t)(e0 + r) * EF_STRIDE + kbase + c * 8);
    }

    // h_src fragments (all 64 rows; both waves need all rows) in registers
    half8 hs[4][4];
#pragma unroll
    for (int rf = 0; rf < 4; ++rf) {
        int s = srcIdx[e0 + rf * 16 + llo];
        const _Float16* hp = hf + (size_t)s * HDIM + lhi * 8;
#pragma unroll
        for (int hc = 0; hc < 4; ++hc)
            hs[rf][hc] = *(const half8*)(hp + hc * 32);
    }

    __syncthreads();   // efs ready (only barrier in the kernel)

    // B fragment (hc, cf) at bp + kk*16384 + hc*4096 + cf*512 (f16 units)
    // chunk index = hc*8 + (chH*4 + w*2 + cf)
    const _Float16* bp = W2L + (size_t)kbase * 16384
                             + (size_t)(chH * 4 + w * 2) * 512 + lane * 8;

#define LDQ(d0, d1, kk, hc) do {                                            \
        const _Float16* p_ = bp + (size_t)(kk) * 16384 + (hc) * 4096;       \
        d0 = *(const half8*)(p_); d1 = *(const half8*)(p_ + 512);           \
    } while (0)

    half8 b00, b01, b10, b11, b20, b21, b30, b31;
    LDQ(b00, b01, 0, 0);
    LDQ(b10, b11, 0, 1);
    LDQ(b20, b21, 0, 2);
    LDQ(b30, b31, 0, 3);

    f32x4 acc[4][2];
#pragma unroll
    for (int rf = 0; rf < 4; ++rf)
#pragma unroll
        for (int cf = 0; cf < 2; ++cf)
#pragma unroll
            for (int d = 0; d < 4; ++d) acc[rf][cf][d] = 0.f;

    for (int kk = 0; kk < kcnt; ++kk) {
        const bool nx = (kk + 1 < kcnt);
        _Float16 efv[4];
#pragma unroll
        for (int rf = 0; rf < 4; ++rf) efv[rf] = efs[rf * 16 + llo][kk];

        __builtin_amdgcn_s_setprio(1);
        // quarter hc=0
#pragma unroll
        for (int rf = 0; rf < 4; ++rf) {
            half8 av = hs[rf][0] * efv[rf];
            acc[rf][0] = __builtin_amdgcn_mfma_f32_16x16x32_f16(av, b00, acc[rf][0], 0, 0, 0);
            acc[rf][1] = __builtin_amdgcn_mfma_f32_16x16x32_f16(av, b01, acc[rf][1], 0, 0, 0);
        }
        if (nx) LDQ(b00, b01, kk + 1, 0);

        // quarter hc=1
#pragma unroll
        for (int rf = 0; rf < 4; ++rf) {
            half8 av = hs[rf][1] * efv[rf];
            acc[rf][0] = __builtin_amdgcn_mfma_f32_16x16x32_f16(av, b10, acc[rf][0], 0, 0, 0);
            acc[rf][1] = __builtin_amdgcn_mfma_f32_16x16x32_f16(av, b11, acc[rf][1], 0, 0, 0);
        }
        if (nx) LDQ(b10, b11, kk + 1, 1);

        // quarter hc=2
#pragma unroll
        for (int rf = 0; rf < 4; ++rf) {
            half8 av = hs[rf][2] * efv[rf];
            acc[rf][0] = __builtin_amdgcn_mfma_f32_16x16x32_f16(av, b20, acc[rf][0], 0, 0, 0);
            acc[rf][1] = __builtin_amdgcn_mfma_f32_16x16x32_f16(av, b21, acc[rf][1], 0, 0, 0);
        }
        if (nx) LDQ(b20, b21, kk + 1, 2);

        // quarter hc=3
#pragma unroll
        for (int rf = 0; rf < 4; ++rf) {
            half8 av = hs[rf][3] * efv[rf];
            acc[rf][0] = __builtin_amdgcn_mfma_f32_16x16x32_f16(av, b30, acc[rf][0], 0, 0, 0);
            acc[rf][1] = __builtin_amdgcn_mfma_f32_16x16x32_f16(av, b31, acc[rf][1], 0, 0, 0);
        }
        __builtin_amdgcn_s_setprio(0);
        if (nx) LDQ(b30, b31, kk + 1, 3);
    }
#undef LDQ

    // epilogue: scatter-add partial msg into agg[dst]
    // C/D layout: col=lane&15, row=(lane>>4)*4+reg
#pragma unroll
    for (int rf = 0; rf < 4; ++rf) {
#pragma unroll
        for (int r = 0; r < 4; ++r) {
            int row = rf * 16 + lhi * 4 + r;
            int d   = dstIdx[e0 + row];
#pragma unroll
            for (int cf = 0; cf < 2; ++cf) {
                int o = chH * 64 + w * 32 + cf * 16 + llo;
                atomicAdd(&agg[(size_t)d * HDIM + o], acc[rf][cf][r]);
            }
        }
    }
}

// out = agg*inv_deg + h @ root_w[l] + conv_b[l]   (16 rows per block)
// also accumulates per-channel batch sum / sumsq for BN (fused bn_stats).
__global__ __launch_bounds__(128)
void k_out(const float* __restrict__ agg, const float* __restrict__ invd,
           const float* __restrict__ h, const float* __restrict__ rw,
           const float* __restrict__ cb, float* __restrict__ outb,
           float* __restrict__ bns1, float* __restrict__ bns2)
{
    __shared__ float hl[16][HDIM];
    int n0 = blockIdx.x * 16, o = threadIdx.x;
    for (int r = 0; r < 16; ++r) hl[r][o] = h[(size_t)(n0 + r) * HDIM + o];
    __syncthreads();
    float acc[16];
    float cbv = cb[o];
#pragma unroll
    for (int r = 0; r < 16; ++r)
        acc[r] = agg[(size_t)(n0 + r) * HDIM + o] * invd[n0 + r] + cbv;
    for (int hh = 0; hh < HDIM; ++hh) {
        float wv = rw[hh * HDIM + o];
#pragma unroll
        for (int r = 0; r < 16; ++r) acc[r] += hl[r][hh] * wv;
    }
    float s1 = 0.f, s2 = 0.f;
#pragma unroll
    for (int r = 0; r < 16; ++r) {
        outb[(size_t)(n0 + r) * HDIM + o] = acc[r];
        s1 += acc[r];
        s2 += acc[r] * acc[r];
    }
    atomicAdd(&bns1[o], s1);
    atomicAdd(&bns2[o], s2);
}

// h += relu(bn(out)) with mu/rsig derived inline; refresh hf.
// Non-last layers: zero agg for the next layer's atomics.
// Last layer: fused global-mean-pool scatter (replaces k_pool).
__global__ void k_bn_apply(const float* __restrict__ outb, const float* __restrict__ bns1,
                           const float* __restrict__ bns2, const float* __restrict__ g,
                           const float* __restrict__ b, float* __restrict__ h,
                           _Float16* __restrict__ hf, float* __restrict__ agg,
                           const int* __restrict__ batch, float* __restrict__ pooled,
                           int* __restrict__ cnt, int last)
{
    int i = blockIdx.x * 256 + threadIdx.x;   // < N*128
    int o = i & (HDIM - 1);
    const float inv_n = 1.0f / (float)N_NODES;
    float m   = bns1[o] * inv_n;
    float var = bns2[o] * inv_n - m * m;
    float rs  = rsqrtf(var + 1e-5f);
    float v  = (outb[i] - m) * rs * g[o] + b[o];
    float hn = h[i] + fmaxf(v, 0.f);
    h[i]  = hn;
    hf[i] = (_Float16)hn;
    if (!last) {
        agg[i] = 0.f;
    } else {
        int n  = i >> 7;
        int gg = batch[n];
        atomicAdd(&pooled[(size_t)gg * HDIM + o], hn);
        if (o == 0) atomicAdd(&cnt[gg], 1);
    }
}

__global__ __launch_bounds__(128)
void k_head(const float* __restrict__ pooled, const int* __restrict__ cnt,
            const float* __restrict__ w1, const float* __restrict__ b1,
            const float* __restrict__ w2, const float* __restrict__ b2,
            float* __restrict__ y)
{
    __shared__ float pl[HDIM];
    __shared__ float red[HDIM];
    int g = blockIdx.x, o = threadIdx.x;
    float ic = 1.0f / (float)max(cnt[g], 1);
    pl[o] = pooled[(size_t)g * HDIM + o] * ic;
    __syncthreads();
    float t = b1[o];
#pragma unroll 8
    for (int hh = 0; hh < HDIM; ++hh) t += pl[hh] * w1[hh * HDIM + o];
    t = fmaxf(t, 0.f);
    red[o] = t * w2[o];
    __syncthreads();
    for (int s = 64; s > 0; s >>= 1) {
        if (o < s) red[o] += red[o + s];
        __syncthreads();
    }
    if (o == 0) y[g] = red[0] + b2[0];
}

// ---------------------------------------------------------------------------
extern "C" void kernel_launch(void* const* d_in, const int* in_sizes, int n_in,
                              void* d_out, int out_size, void* d_ws, size_t ws_size,
                              hipStream_t stream)
{
    const float* x      = (const float*)d_in[0];
    const int*   ei     = (const int*)  d_in[1];
    const float* ea     = (const float*)d_in[2];
    const int*   batch  = (const int*)  d_in[3];
    const float* node_w = (const float*)d_in[4];
    const float* node_b = (const float*)d_in[5];
    const float* e1w    = (const float*)d_in[6];
    const float* e1b    = (const float*)d_in[7];
    const float* e2w    = (const float*)d_in[8];
    const float* e2b    = (const float*)d_in[9];
    const float* rw     = (const float*)d_in[10];
    const float* cb     = (const float*)d_in[11];
    const float* bng    = (const float*)d_in[12];
    const float* bnb    = (const float*)d_in[13];
    const float* hw1    = (const float*)d_in[14];
    const float* hb1    = (const float*)d_in[15];
    const float* hw2    = (const float*)d_in[16];
    const float* hb2    = (const float*)d_in[17];
    float* y = (float*)d_out;

    // workspace carve-up (~27.8 MB, all 256B-aligned chunks)
    char* ws = (char*)d_ws;
    _Float16* W2F  = (_Float16*)ws; ws += 16908288;  // 4*129*16384 f16
    float*    h    = (float*)ws;    ws += 2097152;
    _Float16* hf   = (_Float16*)ws; ws += 1048576;
    _Float16* efg  = (_Float16*)ws; ws += 3342336;   // E*136 f16
    float*    agg  = (float*)ws;    ws += 2097152;   // [N][128] f32
    float*    bns1 = (float*)ws;    ws += 512;       // BN sum
    float*    bns2 = (float*)ws;    ws += 512;       // BN sumsq
    float*    outb = (float*)ws;    ws += 2097152;
    int*      deg  = (int*)ws;      ws += 16384;
    float*    invd = (float*)ws;    ws += 16384;
    float*    pooled = (float*)ws;  ws += 131072;
    int*      cnt  = (int*)ws;      ws += 1024;

    const int* src = ei;
    const int* dst = ei + E_TOT;

    k_prep_w2<<<NLAYER * 129, 256, 0, stream>>>(e2w, e2b, W2F);
    k_node_enc<<<N_NODES, 128, 0, stream>>>(x, node_w, node_b, h, hf);
    hipMemsetAsync(deg, 0, N_NODES * sizeof(int), stream);
    k_deg<<<(E_TOT + 255) / 256, 256, 0, stream>>>(dst, deg);
    k_invd<<<(N_NODES + 255) / 256, 256, 0, stream>>>(deg, invd);
    // agg zero for layer 0; pooled+cnt zero (contiguous => one memset)
    hipMemsetAsync(agg, 0, (size_t)N_NODES * HDIM * sizeof(float), stream);
    hipMemsetAsync(pooled, 0, (size_t)NGRAPH * HDIM * sizeof(float) + NGRAPH * sizeof(int), stream);

    for (int l = 0; l < NLAYER; ++l) {
        k_edge_mlp<<<E_TOT / 16, 256, 0, stream>>>(ea, e1w + l * F_EDGE * HDIM,
                                                   e1b + l * HDIM, efg);
        k_msg<<<(E_TOT / BM) * KSPLIT * 2, 128, 0, stream>>>(
            W2F + (size_t)l * 129 * 16384, efg, hf, src, dst, agg, bns1, bns2);
        k_out<<<N_NODES / 16, 128, 0, stream>>>(agg, invd, h,
                                                rw + l * HDIM * HDIM,
                                                cb + l * HDIM, outb, bns1, bns2);
        k_bn_apply<<<(N_NODES * HDIM) / 256, 256, 0, stream>>>(
            outb, bns1, bns2, bng + l * HDIM, bnb + l * HDIM, h, hf,
            agg, batch, pooled, cnt, (l == NLAYER - 1) ? 1 : 0);
    }

    k_head<<<NGRAPH, 128, 0, stream>>>(pooled, cnt, hw1, hb1, hw2, hb2, y);
}